// Round 3
// baseline (122.365 us; speedup 1.0000x reference)
//
#include <hip/hip_runtime.h>

#define NROWS 8192
#define DIMX  128              // raw feature dims
#define KB    192              // i8 K: 128 data + 40 one-hot (4/class) + 24 zero pad
#define KSEG  12               // 16B segments per row
#define PTB   24576            // bytes per 128-row panel tile (128*192)
#define NKS   3                // MFMA K-steps of 64
#define NCLS  10
#define GAPV  0.4f
#define DEBIAS 504.03125f      // 2*4*127*127/256 — exact fp32
#define SCL   (-0.0078125f)    // -2/256
#define RGR   256              // rows per block (4 waves x 64 rows)
#define NRG   (NROWS / RGR)        // 32 rowgroups
#define CHUNK 512              // cols per block
#define NCHUNK (NROWS / CHUNK)     // 16 col-chunks
#define SLAB  64               // cols per LDS slab
#define NSLAB (CHUNK / SLAB)       // 8 slabs
#define NBLK  (NRG * NCHUNK)       // 512 gram blocks

typedef __attribute__((ext_vector_type(4))) int i32x4;

// async 16B/lane global->LDS DMA
#define GLOAD_LDS16(g, l)                                              \
  __builtin_amdgcn_global_load_lds(                                    \
      (const __attribute__((address_space(1))) void*)(g),              \
      (__attribute__((address_space(3))) void*)(l), 16, 0, 0)

__device__ __forceinline__ int q8(float v) {  // round-to-nearest int8 of 16*x
  int q = (int)rintf(16.f * v);
  return q > 127 ? 127 : (q < -127 ? -127 : q);
}

// order-isomorphic float<->uint encoding: f1 > f2  <=>  ordu(f1) > ordu(f2)
__device__ __forceinline__ unsigned ordu(float f) {
  unsigned b = __float_as_uint(f);
  return (b & 0x80000000u) ? ~b : (b | 0x80000000u);
}
__device__ __forceinline__ float deco(unsigned u) {
  return __uint_as_float((u & 0x80000000u) ? (u ^ 0x80000000u) : ~u);
}

// ---- kernel 1: build i8 PANEL arrays (K=192), sq, confusion, init ctrs/minmax ----
// UNCHANGED from the passing R1 version. Kernel boundary provides cross-XCD
// visibility of all plain stores (panels, sq, conf, inits) — the fused
// grid.sync variant failed exactly here (stale poison-epoch L2 lines).
__global__ __launch_bounds__(256) void prep_k(const float* __restrict__ x,
                                              const int* __restrict__ tgt,
                                              const float* __restrict__ pred,
                                              char* __restrict__ xa,
                                              char* __restrict__ xbm,
                                              float* __restrict__ sq,
                                              int* __restrict__ conf,
                                              unsigned* __restrict__ umax,
                                              unsigned* __restrict__ umin,
                                              unsigned* __restrict__ ctrs) {
  if (blockIdx.x == 0 && threadIdx.x < 3) ctrs[threadIdx.x] = 0u;  // g_done + spare
  if (threadIdx.x < 4) {  // init atomic mining slots for this block's 4 rows
    const int r = blockIdx.x * 4 + threadIdx.x;
    umax[r] = 0u;          // ordu(-inf) lower bound: smallest ordered code
    umin[r] = 0xFFFFFFFFu; // ordu(+inf) upper bound: largest ordered code
  }

  const int wave = threadIdx.x >> 6;
  const int lane = threadIdx.x & 63;
  const int row  = blockIdx.x * 4 + wave;
  const float2 f2 = ((const float2*)(x + (size_t)row * DIMX))[lane];
  float s = f2.x * f2.x + f2.y * f2.y;
  #pragma unroll
  for (int m = 1; m < 64; m <<= 1) s += __shfl_xor(s, m, 64);

  char* basea = xa  + (size_t)(row >> 7) * PTB + (size_t)(row & 127) * 16;
  char* baseb = xbm + (size_t)(row >> 7) * PTB + (size_t)(row & 127) * 16;
  {  // data elems e=2L,2L+1 -> kseg = L>>3, byte (L&7)*2
    const int q0 = q8(f2.x), q1 = q8(f2.y);
    const unsigned short u = (unsigned short)((q0 & 0xFF) | ((q1 & 0xFF) << 8));
    const size_t off = (size_t)(lane >> 3) * 2048 + (lane & 7) * 2;
    *(unsigned short*)(basea + off) = u;
    *(unsigned short*)(baseb + off) = u;
  }
  const int cls = tgt[row];
  if (lane < 32) {  // aug elems e = 128 + j, j = 2*lane, 2*lane+1
    const int j = 2 * lane;
    const int c = j >> 2;                  // class block (4 dims each)
    const bool hit = (c < NCLS) && (c == cls);
    const unsigned short ua = hit ? (unsigned short)0x7F7F : 0;  // +127,+127
    const unsigned short ub = hit ? (unsigned short)0x8181 : 0;  // -127,-127
    const size_t off = (size_t)(8 + (j >> 4)) * 2048 + (j & 15);
    *(unsigned short*)(basea + off) = ua;
    *(unsigned short*)(baseb + off) = ub;
  }

  if (lane == 0) {
    sq[row] = s;
    const float* pp = pred + (size_t)row * NCLS;
    float v[NCLS];
    #pragma unroll
    for (int c = 0; c < NCLS; ++c) v[c] = pp[c];
    float m1 = v[0]; int i1 = 0;
    #pragma unroll
    for (int c = 1; c < NCLS; ++c)
      if (v[c] > m1) { m1 = v[c]; i1 = c; }
    float m2 = -INFINITY, sum = 0.f;
    #pragma unroll
    for (int c = 0; c < NCLS; ++c) {
      sum += __expf(v[c] - m1);
      if (c != i1) m2 = fmaxf(m2, v[c]);
    }
    const float d01 = (1.f - __expf(m2 - m1)) / sum;
    conf[row] = (d01 <= GAPV) || (i1 != cls);
  }
}

// ---- kernel 2: Gram + hard mining + LAST-BLOCK-DONE loss tail ----
// Mining exits via ordered-uint device-scope atomics (coherent across XCDs).
// The 512th block to arrive at g_done decodes all 8192 rows and writes out[0]:
// removes the reduce_k dispatch + one launch boundary. Tail reads umax/umin via
// atomicOr (device-scope), sq/conf via plain loads (prior-kernel data — the
// exact access pattern the 3-kernel version proved coherent).
__global__ __launch_bounds__(256)
__attribute__((amdgpu_waves_per_eu(3, 4)))
void gram_k(const char* __restrict__ xa,
            const char* __restrict__ xbm,
            const float* __restrict__ sq,
            const int* __restrict__ conf,
            unsigned* __restrict__ umax,
            unsigned* __restrict__ umin,
            unsigned* __restrict__ ctrs,
            float* __restrict__ out) {
  __shared__ char  ldsb[2][KSEG * 1024];   // per buf: 12 ksegs x 64 cols x 16B = 12 KB
  __shared__ float sqb[2][SLAB];
  __shared__ unsigned last_flag;
  const int tid  = threadIdx.x;
  const int wave = tid >> 6;
  const int lane = tid & 63;
  const int quad = lane >> 4;   // 0..3
  const int m16  = lane & 15;   // 0..15
  const int bx = blockIdx.x, by = blockIdx.y;

  // A fragments: rows bx*256 + wave*64 + rt*16 + m16, kseg = ks*4 + quad
  i32x4 A[4][NKS];
  #pragma unroll
  for (int rt = 0; rt < 4; ++rt) {
    const int rbase = wave * 64 + rt * 16;               // 0..240 within block rows
    const char* pa = xa + (size_t)(bx * 2 + (rbase >> 7)) * PTB
                        + (size_t)((rbase & 127) + m16) * 16;
    #pragma unroll
    for (int ks = 0; ks < NKS; ++ks)
      A[rt][ks] = *(const i32x4*)(pa + (size_t)(ks * 4 + quad) * 2048);
  }
  #pragma unroll
  for (int rt = 0; rt < 4; ++rt)
    #pragma unroll
    for (int ks = 0; ks < NKS; ++ks)
      asm("" : "+v"(A[rt][ks]));   // keep A resident

  float gmin[4][4], gmax[4][4];
  #pragma unroll
  for (int r = 0; r < 4; ++r)
    #pragma unroll
    for (int q = 0; q < 4; ++q) { gmin[r][q] = INFINITY; gmax[r][q] = -INFINITY; }

  // DMA slab 0: wave w stages ksegs 3w..3w+2; wave 3 lanes<16 also stage sq (64 floats)
  {
    const char* srcb = xbm + (size_t)(by * 4) * PTB;
    #pragma unroll
    for (int u = 0; u < 3; ++u) {
      const int kseg = wave * 3 + u;
      GLOAD_LDS16(srcb + (size_t)kseg * 2048 + lane * 16, &ldsb[0][kseg * 1024 + lane * 16]);
    }
    if (wave == 3 && lane < 16)
      GLOAD_LDS16((const char*)(sq + by * CHUNK) + lane * 16, (char*)&sqb[0][0] + lane * 16);
  }

  for (int s = 0; s < NSLAB; ++s) {
    __syncthreads();   // drains this wave's DMA + syncs buf ready
    if (s + 1 < NSLAB) {
      const char* srcb = xbm + (size_t)(by * 4 + ((s + 1) >> 1)) * PTB + ((s + 1) & 1) * 1024;
      char* dstb = &ldsb[(s + 1) & 1][0];
      #pragma unroll
      for (int u = 0; u < 3; ++u) {
        const int kseg = wave * 3 + u;
        GLOAD_LDS16(srcb + (size_t)kseg * 2048 + lane * 16, dstb + kseg * 1024 + lane * 16);
      }
      if (wave == 3 && lane < 16)
        GLOAD_LDS16((const char*)(sq + by * CHUNK + (s + 1) * SLAB) + lane * 16,
                    (char*)&sqb[(s + 1) & 1][0] + lane * 16);
    }
    // compute slab s: 4 j-tiles of 16 cols
    const char* buf = &ldsb[s & 1][0];
    #pragma unroll
    for (int jt = 0; jt < 4; ++jt) {
      i32x4 B[NKS];
      #pragma unroll
      for (int ks = 0; ks < NKS; ++ks)
        B[ks] = *(const i32x4*)(buf + (ks * 4 + quad) * 1024 + (jt * 16 + m16) * 16);
      const float sqj = sqb[s & 1][jt * 16 + m16];

      i32x4 acc[4];
      #pragma unroll
      for (int r = 0; r < 4; ++r) acc[r] = (i32x4){0, 0, 0, 0};
      #pragma unroll
      for (int ks = 0; ks < NKS; ++ks)
        #pragma unroll
        for (int r = 0; r < 4; ++r)
          acc[r] = __builtin_amdgcn_mfma_i32_16x16x64_i8(A[r][ks], B[ks], acc[r], 0, 0, 0);

      #pragma unroll
      for (int r = 0; r < 4; ++r)
        #pragma unroll
        for (int q = 0; q < 4; ++q) {
          const float cand = fmaf((float)acc[r][q], SCL, sqj);  // sq_j - 2dot + 504.03*same
          gmin[r][q] = fminf(gmin[r][q], cand);
          gmax[r][q] = fmaxf(gmax[r][q], cand);
        }
    }
  }

  // reduce over the 16 cols held across m16 lanes (quad bits preserved)
  #pragma unroll
  for (int m = 1; m <= 8; m <<= 1)
    #pragma unroll
    for (int r = 0; r < 4; ++r)
      #pragma unroll
      for (int q = 0; q < 4; ++q) {
        gmin[r][q] = fminf(gmin[r][q], __shfl_xor(gmin[r][q], m, 64));
        gmax[r][q] = fmaxf(gmax[r][q], __shfl_xor(gmax[r][q], m, 64));
      }

  if (m16 == 0) {  // lanes 0/16/32/48: quad q-block of 4 consecutive rows per r-tile
    const int rowb = bx * RGR + wave * 64 + quad * 4;
    #pragma unroll
    for (int r = 0; r < 4; ++r)
      #pragma unroll
      for (int q = 0; q < 4; ++q) {
        atomicMax(&umax[rowb + r * 16 + q], ordu(gmax[r][q]));
        atomicMin(&umin[rowb + r * 16 + q], ordu(gmin[r][q]));
      }
  }

  // ---- last-block-done tail ----
  __threadfence();      // each thread: drain + make own atomics device-visible
  __syncthreads();      // all waves of this block done mining
  if (tid == 0) last_flag = (atomicAdd(&ctrs[0], 1u) == NBLK - 1u) ? 1u : 0u;
  __syncthreads();
  if (last_flag) {      // exactly one block, after ALL blocks' atomics completed
    float ps = 0.f, pc = 0.f;
    #pragma unroll
    for (int i = 0; i < NROWS / 256; ++i) {   // 32 rows/thread, stride-256 coalesced
      const int row = i * 256 + tid;
      const float hi = deco(atomicOr(&umax[row], 0u));   // device-scope reads
      const float lo = deco(atomicOr(&umin[row], 0u));
      if (conf[row]) {
        const float ap = sqrtf(fmaxf(sq[row] + hi - DEBIAS, 1e-12f));  // hardest positive
        const float an = sqrtf(fmaxf(sq[row] + lo, 1e-12f));           // hardest negative
        ps += fmaxf(ap - an, 0.f);
        pc += 1.f;
      }
    }
    #pragma unroll
    for (int m = 1; m < 64; m <<= 1) {
      ps += __shfl_xor(ps, m, 64);
      pc += __shfl_xor(pc, m, 64);
    }
    __shared__ float red[2][4];
    if (lane == 0) { red[0][wave] = ps; red[1][wave] = pc; }
    __syncthreads();
    if (tid == 0) {
      const float St = red[0][0] + red[0][1] + red[0][2] + red[0][3];
      const float Ct = red[1][0] + red[1][1] + red[1][2] + red[1][3];
      out[0] = (Ct > 0.f) ? (St / fmaxf(Ct, 1.f)) : 0.f;
    }
  }
}

extern "C" void kernel_launch(void* const* d_in, const int* in_sizes, int n_in,
                              void* d_out, int out_size, void* d_ws, size_t ws_size,
                              hipStream_t stream) {
  const float* x    = (const float*)d_in[0];
  const float* pred = (const float*)d_in[1];
  const int*   tgt  = (const int*)d_in[2];
  float* out = (float*)d_out;

  char* w = (char*)d_ws;
  const size_t arr_bytes = (size_t)NROWS * KB;   // 1.57 MiB each (i8 panel layout)
  char*     xa   = w;
  char*     xbm  = w + arr_bytes;
  float*    sq   = (float*)(w + 2 * arr_bytes);
  int*      conf = (int*)(w + 2 * arr_bytes + (size_t)NROWS * 4);
  unsigned* umax = (unsigned*)(w + 2 * arr_bytes + (size_t)NROWS * 8);
  unsigned* umin = (unsigned*)(w + 2 * arr_bytes + (size_t)NROWS * 12);
  unsigned* ctrs = (unsigned*)(w + 2 * arr_bytes + (size_t)NROWS * 16);

  hipLaunchKernelGGL(prep_k, dim3(NROWS / 4), dim3(256), 0, stream,
                     x, tgt, pred, xa, xbm, sq, conf, umax, umin, ctrs);
  hipLaunchKernelGGL(gram_k, dim3(NRG, NCHUNK), dim3(256), 0, stream,
                     xa, xbm, sq, conf, umax, umin, ctrs, out);
}

// Round 4
// 88.228 us; speedup vs baseline: 1.3869x; 1.3869x over previous
//
#include <hip/hip_runtime.h>

#define NROWS 8192
#define DIMX  128              // raw feature dims
#define KB    192              // i8 K: 128 data + 40 one-hot (4/class) + 24 zero pad
#define KSEG  12               // 16B segments per row
#define PTB   24576            // bytes per 128-row panel tile (128*192)
#define NKS   3                // MFMA K-steps of 64
#define NCLS  10
#define GAPV  0.4f
#define DEBIAS 504.03125f      // 2*4*127*127/256 — exact fp32
#define SCL   (-0.0078125f)    // -2/256
#define RGR   256              // rows per block (4 waves x 64 rows)
#define NRG   (NROWS / RGR)        // 32 rowgroups
#define CHUNK 256              // cols per block (R4: halved -> 2x blocks for TLP)
#define NCHUNK (NROWS / CHUNK)     // 32 col-chunks
#define SLAB  64               // cols per LDS slab
#define NSLAB (CHUNK / SLAB)       // 4 slabs

typedef __attribute__((ext_vector_type(4))) int i32x4;

// async 16B/lane global->LDS DMA
#define GLOAD_LDS16(g, l)                                              \
  __builtin_amdgcn_global_load_lds(                                    \
      (const __attribute__((address_space(1))) void*)(g),              \
      (__attribute__((address_space(3))) void*)(l), 16, 0, 0)

__device__ __forceinline__ int q8(float v) {  // round-to-nearest int8 of 16*x
  int q = (int)rintf(16.f * v);
  return q > 127 ? 127 : (q < -127 ? -127 : q);
}

// order-isomorphic float<->uint encoding: f1 > f2  <=>  ordu(f1) > ordu(f2)
__device__ __forceinline__ unsigned ordu(float f) {
  unsigned b = __float_as_uint(f);
  return (b & 0x80000000u) ? ~b : (b | 0x80000000u);
}
__device__ __forceinline__ float deco(unsigned u) {
  return __uint_as_float((u & 0x80000000u) ? (u ^ 0x80000000u) : ~u);
}

// ---- kernel 1: build i8 PANEL arrays (K=192), sq, confusion, init ctrs/minmax ----
// Bit-identical to the passing R1 version.
__global__ __launch_bounds__(256) void prep_k(const float* __restrict__ x,
                                              const int* __restrict__ tgt,
                                              const float* __restrict__ pred,
                                              char* __restrict__ xa,
                                              char* __restrict__ xbm,
                                              float* __restrict__ sq,
                                              int* __restrict__ conf,
                                              unsigned* __restrict__ umax,
                                              unsigned* __restrict__ umin,
                                              unsigned* __restrict__ ctrs) {
  if (blockIdx.x == 0 && threadIdx.x < 3) ctrs[threadIdx.x] = 0u;
  if (threadIdx.x < 4) {  // init atomic mining slots for this block's 4 rows
    const int r = blockIdx.x * 4 + threadIdx.x;
    umax[r] = 0u;          // ordu(-inf)
    umin[r] = 0xFFFFFFFFu; // ordu(+inf)
  }

  const int wave = threadIdx.x >> 6;
  const int lane = threadIdx.x & 63;
  const int row  = blockIdx.x * 4 + wave;
  const float2 f2 = ((const float2*)(x + (size_t)row * DIMX))[lane];
  float s = f2.x * f2.x + f2.y * f2.y;
  #pragma unroll
  for (int m = 1; m < 64; m <<= 1) s += __shfl_xor(s, m, 64);

  char* basea = xa  + (size_t)(row >> 7) * PTB + (size_t)(row & 127) * 16;
  char* baseb = xbm + (size_t)(row >> 7) * PTB + (size_t)(row & 127) * 16;
  {  // data elems e=2L,2L+1 -> kseg = L>>3, byte (L&7)*2
    const int q0 = q8(f2.x), q1 = q8(f2.y);
    const unsigned short u = (unsigned short)((q0 & 0xFF) | ((q1 & 0xFF) << 8));
    const size_t off = (size_t)(lane >> 3) * 2048 + (lane & 7) * 2;
    *(unsigned short*)(basea + off) = u;
    *(unsigned short*)(baseb + off) = u;
  }
  const int cls = tgt[row];
  if (lane < 32) {  // aug elems e = 128 + j, j = 2*lane, 2*lane+1
    const int j = 2 * lane;
    const int c = j >> 2;                  // class block (4 dims each)
    const bool hit = (c < NCLS) && (c == cls);
    const unsigned short ua = hit ? (unsigned short)0x7F7F : 0;  // +127,+127
    const unsigned short ub = hit ? (unsigned short)0x8181 : 0;  // -127,-127
    const size_t off = (size_t)(8 + (j >> 4)) * 2048 + (j & 15);
    *(unsigned short*)(basea + off) = ua;
    *(unsigned short*)(baseb + off) = ub;
  }

  if (lane == 0) {
    sq[row] = s;
    const float* pp = pred + (size_t)row * NCLS;
    float v[NCLS];
    #pragma unroll
    for (int c = 0; c < NCLS; ++c) v[c] = pp[c];
    float m1 = v[0]; int i1 = 0;
    #pragma unroll
    for (int c = 1; c < NCLS; ++c)
      if (v[c] > m1) { m1 = v[c]; i1 = c; }
    float m2 = -INFINITY, sum = 0.f;
    #pragma unroll
    for (int c = 0; c < NCLS; ++c) {
      sum += __expf(v[c] - m1);
      if (c != i1) m2 = fmaxf(m2, v[c]);
    }
    const float d01 = (1.f - __expf(m2 - m1)) / sum;
    conf[row] = (d01 <= GAPV) || (i1 != cls);
  }
}

// ---- kernel 2: PURE Gram + hard mining. R4: CHUNK=256 -> 1024 blocks ----
// R3 diagnosis: 512 blocks = 2 serial blocks/CU, both pipes <13% busy, the
// per-slab barrier vmcnt-drain had no TLP cover. Resources allow ~6 blocks/CU
// (VGPR 76, LDS 25.6KB); grid size was the occupancy limiter. 1024 blocks give
// 4 co-resident blocks/CU; waves_per_eu max raised 4->8 to permit it (min=3
// keeps the VGPR budget >=170: A stays in registers, no spill).
// NO tail / NO threadfence here (R3's per-block device fence cost ~2x).
__global__ __launch_bounds__(256)
__attribute__((amdgpu_waves_per_eu(3, 8)))
void gram_k(const char* __restrict__ xa,
            const char* __restrict__ xbm,
            const float* __restrict__ sq,
            unsigned* __restrict__ umax,
            unsigned* __restrict__ umin) {
  __shared__ char  ldsb[2][KSEG * 1024];   // per buf: 12 ksegs x 64 cols x 16B = 12 KB
  __shared__ float sqb[2][SLAB];
  const int tid  = threadIdx.x;
  const int wave = tid >> 6;
  const int lane = tid & 63;
  const int quad = lane >> 4;   // 0..3
  const int m16  = lane & 15;   // 0..15
  const int bx = blockIdx.x, by = blockIdx.y;

  // A fragments: rows bx*256 + wave*64 + rt*16 + m16, kseg = ks*4 + quad
  i32x4 A[4][NKS];
  #pragma unroll
  for (int rt = 0; rt < 4; ++rt) {
    const int rbase = wave * 64 + rt * 16;               // 0..240 within block rows
    const char* pa = xa + (size_t)(bx * 2 + (rbase >> 7)) * PTB
                        + (size_t)((rbase & 127) + m16) * 16;
    #pragma unroll
    for (int ks = 0; ks < NKS; ++ks)
      A[rt][ks] = *(const i32x4*)(pa + (size_t)(ks * 4 + quad) * 2048);
  }
  #pragma unroll
  for (int rt = 0; rt < 4; ++rt)
    #pragma unroll
    for (int ks = 0; ks < NKS; ++ks)
      asm("" : "+v"(A[rt][ks]));   // keep A resident

  float gmin[4][4], gmax[4][4];
  #pragma unroll
  for (int r = 0; r < 4; ++r)
    #pragma unroll
    for (int q = 0; q < 4; ++q) { gmin[r][q] = INFINITY; gmax[r][q] = -INFINITY; }

  // DMA slab 0: wave w stages ksegs 3w..3w+2; wave 3 lanes<16 also stage sq (64 floats)
  // col base for slab s: by*CHUNK + s*64 -> panel (by*2 + (s>>1)), byte off (s&1)*1024
  {
    const char* srcb = xbm + (size_t)(by * 2) * PTB;
    #pragma unroll
    for (int u = 0; u < 3; ++u) {
      const int kseg = wave * 3 + u;
      GLOAD_LDS16(srcb + (size_t)kseg * 2048 + lane * 16, &ldsb[0][kseg * 1024 + lane * 16]);
    }
    if (wave == 3 && lane < 16)
      GLOAD_LDS16((const char*)(sq + by * CHUNK) + lane * 16, (char*)&sqb[0][0] + lane * 16);
  }

  for (int s = 0; s < NSLAB; ++s) {
    __syncthreads();   // drains this wave's DMA + syncs buf ready
    if (s + 1 < NSLAB) {
      const char* srcb = xbm + (size_t)(by * 2 + ((s + 1) >> 1)) * PTB + ((s + 1) & 1) * 1024;
      char* dstb = &ldsb[(s + 1) & 1][0];
      #pragma unroll
      for (int u = 0; u < 3; ++u) {
        const int kseg = wave * 3 + u;
        GLOAD_LDS16(srcb + (size_t)kseg * 2048 + lane * 16, dstb + kseg * 1024 + lane * 16);
      }
      if (wave == 3 && lane < 16)
        GLOAD_LDS16((const char*)(sq + by * CHUNK + (s + 1) * SLAB) + lane * 16,
                    (char*)&sqb[(s + 1) & 1][0] + lane * 16);
    }
    // compute slab s: 4 j-tiles of 16 cols
    const char* buf = &ldsb[s & 1][0];
    #pragma unroll
    for (int jt = 0; jt < 4; ++jt) {
      i32x4 B[NKS];
      #pragma unroll
      for (int ks = 0; ks < NKS; ++ks)
        B[ks] = *(const i32x4*)(buf + (ks * 4 + quad) * 1024 + (jt * 16 + m16) * 16);
      const float sqj = sqb[s & 1][jt * 16 + m16];

      i32x4 acc[4];
      #pragma unroll
      for (int r = 0; r < 4; ++r) acc[r] = (i32x4){0, 0, 0, 0};
      #pragma unroll
      for (int ks = 0; ks < NKS; ++ks)
        #pragma unroll
        for (int r = 0; r < 4; ++r)
          acc[r] = __builtin_amdgcn_mfma_i32_16x16x64_i8(A[r][ks], B[ks], acc[r], 0, 0, 0);

      #pragma unroll
      for (int r = 0; r < 4; ++r)
        #pragma unroll
        for (int q = 0; q < 4; ++q) {
          const float cand = fmaf((float)acc[r][q], SCL, sqj);  // sq_j - 2dot + 504.03*same
          gmin[r][q] = fminf(gmin[r][q], cand);
          gmax[r][q] = fmaxf(gmax[r][q], cand);
        }
    }
  }

  // reduce over the 16 cols held across m16 lanes (quad bits preserved)
  #pragma unroll
  for (int m = 1; m <= 8; m <<= 1)
    #pragma unroll
    for (int r = 0; r < 4; ++r)
      #pragma unroll
      for (int q = 0; q < 4; ++q) {
        gmin[r][q] = fminf(gmin[r][q], __shfl_xor(gmin[r][q], m, 64));
        gmax[r][q] = fmaxf(gmax[r][q], __shfl_xor(gmax[r][q], m, 64));
      }

  if (m16 == 0) {  // lanes 0/16/32/48: quad q-block of 4 consecutive rows per r-tile
    const int rowb = bx * RGR + wave * 64 + quad * 4;
    #pragma unroll
    for (int r = 0; r < 4; ++r)
      #pragma unroll
      for (int q = 0; q < 4; ++q) {
        atomicMax(&umax[rowb + r * 16 + q], ordu(gmax[r][q]));
        atomicMin(&umin[rowb + r * 16 + q], ordu(gmin[r][q]));
      }
  }
}

// ---- kernel 3: per-row decode + loss (32 blocks x 256 threads, 1 row/thread) ----
// Bit-identical to the passing R1 version.
__global__ __launch_bounds__(256) void reduce_k(const unsigned* __restrict__ umax,
                                                const unsigned* __restrict__ umin,
                                                const float* __restrict__ sq,
                                                const int* __restrict__ conf,
                                                unsigned* __restrict__ ctrs,
                                                float* __restrict__ out) {
  __shared__ float red[2][4];
  const int tid = threadIdx.x, bx = blockIdx.x;
  const int wave = tid >> 6, lane = tid & 63;
  const int row = bx * RGR + tid;

  unsigned* g_done = ctrs;
  float*    Ssum   = (float*)(ctrs + 1);
  float*    Csum   = (float*)(ctrs + 2);

  const float hi = deco(umax[row]);
  const float lo = deco(umin[row]);
  float ps = 0.f, pc = 0.f;
  if (conf[row]) {
    const float ap = sqrtf(fmaxf(sq[row] + hi - DEBIAS, 1e-12f));  // hardest positive
    const float an = sqrtf(fmaxf(sq[row] + lo, 1e-12f));           // hardest negative
    ps = fmaxf(ap - an, 0.f);
    pc = 1.f;
  }
  #pragma unroll
  for (int m = 1; m < 64; m <<= 1) {
    ps += __shfl_xor(ps, m, 64);
    pc += __shfl_xor(pc, m, 64);
  }
  if (lane == 0) { red[0][wave] = ps; red[1][wave] = pc; }
  __syncthreads();
  if (tid == 0) {
    atomicAdd(Ssum, red[0][0] + red[0][1] + red[0][2] + red[0][3]);
    atomicAdd(Csum, red[1][0] + red[1][1] + red[1][2] + red[1][3]);
    __threadfence();
    if (atomicAdd(g_done, 1u) == NRG - 1u) {
      const float St = atomicAdd(Ssum, 0.f);
      const float Ct = atomicAdd(Csum, 0.f);
      out[0] = (Ct > 0.f) ? (St / fmaxf(Ct, 1.f)) : 0.f;
    }
  }
}

extern "C" void kernel_launch(void* const* d_in, const int* in_sizes, int n_in,
                              void* d_out, int out_size, void* d_ws, size_t ws_size,
                              hipStream_t stream) {
  const float* x    = (const float*)d_in[0];
  const float* pred = (const float*)d_in[1];
  const int*   tgt  = (const int*)d_in[2];
  float* out = (float*)d_out;

  char* w = (char*)d_ws;
  const size_t arr_bytes = (size_t)NROWS * KB;   // 1.57 MiB each (i8 panel layout)
  char*     xa   = w;
  char*     xbm  = w + arr_bytes;
  float*    sq   = (float*)(w + 2 * arr_bytes);
  int*      conf = (int*)(w + 2 * arr_bytes + (size_t)NROWS * 4);
  unsigned* umax = (unsigned*)(w + 2 * arr_bytes + (size_t)NROWS * 8);
  unsigned* umin = (unsigned*)(w + 2 * arr_bytes + (size_t)NROWS * 12);
  unsigned* ctrs = (unsigned*)(w + 2 * arr_bytes + (size_t)NROWS * 16);

  hipLaunchKernelGGL(prep_k, dim3(NROWS / 4), dim3(256), 0, stream,
                     x, tgt, pred, xa, xbm, sq, conf, umax, umin, ctrs);
  hipLaunchKernelGGL(gram_k, dim3(NRG, NCHUNK), dim3(256), 0, stream,
                     xa, xbm, sq, umax, umin);
  hipLaunchKernelGGL(reduce_k, dim3(NRG), dim3(256), 0, stream,
                     umax, umin, sq, conf, ctrs, out);
}

// Round 5
// 86.145 us; speedup vs baseline: 1.4204x; 1.0242x over previous
//
#include <hip/hip_runtime.h>

#define NROWS 8192
#define DIMX  128              // raw feature dims
#define KB    192              // i8 K: 128 data + 40 one-hot (4/class) + 24 zero pad
#define KSEG  12               // 16B segments per row
#define PTB   24576            // bytes per 128-row panel tile (128*192)
#define NKS   3                // MFMA K-steps of 64
#define NCLS  10
#define GAPV  0.4f
#define DEBIAS 504.03125f      // 2*4*127*127/256 — exact fp32
#define SCL   (-0.0078125f)    // -2/256
#define RGR   256              // rows per block (4 waves x 64 rows)
#define NRG   (NROWS / RGR)        // 32 rowgroups
#define CHUNK 512              // cols per block
#define NCHUNK (NROWS / CHUNK)     // 16 col-chunks
#define NT    (CHUNK / 16)         // 32 column tiles of 16

typedef __attribute__((ext_vector_type(4))) int i32x4;

__device__ __forceinline__ int q8(float v) {  // round-to-nearest int8 of 16*x
  int q = (int)rintf(16.f * v);
  return q > 127 ? 127 : (q < -127 ? -127 : q);
}

// order-isomorphic float<->uint encoding: f1 > f2  <=>  ordu(f1) > ordu(f2)
__device__ __forceinline__ unsigned ordu(float f) {
  unsigned b = __float_as_uint(f);
  return (b & 0x80000000u) ? ~b : (b | 0x80000000u);
}
__device__ __forceinline__ float deco(unsigned u) {
  return __uint_as_float((u & 0x80000000u) ? (u ^ 0x80000000u) : ~u);
}

// ---- kernel 1: build i8 PANEL arrays (K=192), sq, confusion, init ctrs/minmax ----
// Bit-identical to the passing R1 version.
__global__ __launch_bounds__(256) void prep_k(const float* __restrict__ x,
                                              const int* __restrict__ tgt,
                                              const float* __restrict__ pred,
                                              char* __restrict__ xa,
                                              char* __restrict__ xbm,
                                              float* __restrict__ sq,
                                              int* __restrict__ conf,
                                              unsigned* __restrict__ umax,
                                              unsigned* __restrict__ umin,
                                              unsigned* __restrict__ ctrs) {
  if (blockIdx.x == 0 && threadIdx.x < 3) ctrs[threadIdx.x] = 0u;
  if (threadIdx.x < 4) {  // init atomic mining slots for this block's 4 rows
    const int r = blockIdx.x * 4 + threadIdx.x;
    umax[r] = 0u;          // ordu(-inf)
    umin[r] = 0xFFFFFFFFu; // ordu(+inf)
  }

  const int wave = threadIdx.x >> 6;
  const int lane = threadIdx.x & 63;
  const int row  = blockIdx.x * 4 + wave;
  const float2 f2 = ((const float2*)(x + (size_t)row * DIMX))[lane];
  float s = f2.x * f2.x + f2.y * f2.y;
  #pragma unroll
  for (int m = 1; m < 64; m <<= 1) s += __shfl_xor(s, m, 64);

  char* basea = xa  + (size_t)(row >> 7) * PTB + (size_t)(row & 127) * 16;
  char* baseb = xbm + (size_t)(row >> 7) * PTB + (size_t)(row & 127) * 16;
  {  // data elems e=2L,2L+1 -> kseg = L>>3, byte (L&7)*2
    const int q0 = q8(f2.x), q1 = q8(f2.y);
    const unsigned short u = (unsigned short)((q0 & 0xFF) | ((q1 & 0xFF) << 8));
    const size_t off = (size_t)(lane >> 3) * 2048 + (lane & 7) * 2;
    *(unsigned short*)(basea + off) = u;
    *(unsigned short*)(baseb + off) = u;
  }
  const int cls = tgt[row];
  if (lane < 32) {  // aug elems e = 128 + j, j = 2*lane, 2*lane+1
    const int j = 2 * lane;
    const int c = j >> 2;                  // class block (4 dims each)
    const bool hit = (c < NCLS) && (c == cls);
    const unsigned short ua = hit ? (unsigned short)0x7F7F : 0;  // +127,+127
    const unsigned short ub = hit ? (unsigned short)0x8181 : 0;  // -127,-127
    const size_t off = (size_t)(8 + (j >> 4)) * 2048 + (j & 15);
    *(unsigned short*)(basea + off) = ua;
    *(unsigned short*)(baseb + off) = ub;
  }

  if (lane == 0) {
    sq[row] = s;
    const float* pp = pred + (size_t)row * NCLS;
    float v[NCLS];
    #pragma unroll
    for (int c = 0; c < NCLS; ++c) v[c] = pp[c];
    float m1 = v[0]; int i1 = 0;
    #pragma unroll
    for (int c = 1; c < NCLS; ++c)
      if (v[c] > m1) { m1 = v[c]; i1 = c; }
    float m2 = -INFINITY, sum = 0.f;
    #pragma unroll
    for (int c = 0; c < NCLS; ++c) {
      sum += __expf(v[c] - m1);
      if (c != i1) m2 = fmaxf(m2, v[c]);
    }
    const float d01 = (1.f - __expf(m2 - m1)) / sum;
    conf[row] = (d01 <= GAPV) || (i1 != cls);
  }
}

// ---- kernel 2: Gram + hard mining — R5: BARRIER-FREE, NO LDS ----
// R3/R4 diagnosis: per-slab __syncthreads (vmcnt drain) serialized 4 waves 8x
// per block; MfmaUtil 7%. B is only 1.5 MB (L2-resident), and LDS staging gave
// only 4x reuse — so read B fragments DIRECTLY from global (coalesced 16B/lane,
// L2-hit) with 1-tile register double-buffering. Zero barriers, zero LDS:
// waves free-run, latency hidden by ILP (prefetch issued before 12 MFMAs)
// + 8-12 resident waves/CU. Extra L2 traffic ~100 MB @ 34 TB/s ~ 3 us.
__global__ __launch_bounds__(256)
__attribute__((amdgpu_waves_per_eu(3, 8)))
void gram_k(const char* __restrict__ xa,
            const char* __restrict__ xbm,
            const float* __restrict__ sq,
            unsigned* __restrict__ umax,
            unsigned* __restrict__ umin) {
  const int tid  = threadIdx.x;
  const int wave = tid >> 6;
  const int lane = tid & 63;
  const int quad = lane >> 4;   // 0..3
  const int m16  = lane & 15;   // 0..15
  const int bx = blockIdx.x, by = blockIdx.y;

  // A fragments: rows bx*256 + wave*64 + rt*16 + m16, kseg = ks*4 + quad
  i32x4 A[4][NKS];
  #pragma unroll
  for (int rt = 0; rt < 4; ++rt) {
    const int rbase = wave * 64 + rt * 16;               // 0..240 within block rows
    const char* pa = xa + (size_t)(bx * 2 + (rbase >> 7)) * PTB
                        + (size_t)((rbase & 127) + m16) * 16;
    #pragma unroll
    for (int ks = 0; ks < NKS; ++ks)
      A[rt][ks] = *(const i32x4*)(pa + (size_t)(ks * 4 + quad) * 2048);
  }
  #pragma unroll
  for (int rt = 0; rt < 4; ++rt)
    #pragma unroll
    for (int ks = 0; ks < NKS; ++ks)
      asm("" : "+v"(A[rt][ks]));   // keep A resident

  float gmin[4][4], gmax[4][4];
  #pragma unroll
  for (int r = 0; r < 4; ++r)
    #pragma unroll
    for (int q = 0; q < 4; ++q) { gmin[r][q] = INFINITY; gmax[r][q] = -INFINITY; }

  // per-lane invariant B base: col-panel group by*4, this lane's m16/quad slot
  // tile u (0..31): addr = bl + (u>>3)*PTB + (u&7)*256 + ks*8192
  const char*  bl  = xbm + (size_t)(by * 4) * PTB + (size_t)m16 * 16 + (size_t)quad * 2048;
  const float* sqp = sq + by * CHUNK + m16;

  i32x4 Bc[NKS], Bn[NKS];
  float sqc, sqn;
  #pragma unroll
  for (int ks = 0; ks < NKS; ++ks) Bc[ks] = *(const i32x4*)(bl + ks * 8192);
  sqc = sqp[0];

  for (int s = 0; s < NT / 4; ++s) {        // 8 groups of 4 tiles
    #pragma unroll
    for (int jt = 0; jt < 4; ++jt) {
      const int u  = s * 4 + jt;
      const int un = (u + 1 < NT) ? u + 1 : NT - 1;   // clamp: last prefetch redundant
      const size_t toff = (size_t)(un >> 3) * PTB + (size_t)(un & 7) * 256;
      #pragma unroll
      for (int ks = 0; ks < NKS; ++ks)
        Bn[ks] = *(const i32x4*)(bl + toff + ks * 8192);
      sqn = sqp[un * 16];

      i32x4 acc[4];
      #pragma unroll
      for (int r = 0; r < 4; ++r) acc[r] = (i32x4){0, 0, 0, 0};
      #pragma unroll
      for (int ks = 0; ks < NKS; ++ks)
        #pragma unroll
        for (int r = 0; r < 4; ++r)
          acc[r] = __builtin_amdgcn_mfma_i32_16x16x64_i8(A[r][ks], Bc[ks], acc[r], 0, 0, 0);

      #pragma unroll
      for (int r = 0; r < 4; ++r)
        #pragma unroll
        for (int q = 0; q < 4; ++q) {
          const float cand = fmaf((float)acc[r][q], SCL, sqc);  // sq_j - 2dot + 504.03*same
          gmin[r][q] = fminf(gmin[r][q], cand);
          gmax[r][q] = fmaxf(gmax[r][q], cand);
        }

      #pragma unroll
      for (int ks = 0; ks < NKS; ++ks) Bc[ks] = Bn[ks];   // renamed away by unroll
      sqc = sqn;
    }
  }

  // reduce over the 16 cols held across m16 lanes (quad bits preserved)
  #pragma unroll
  for (int m = 1; m <= 8; m <<= 1)
    #pragma unroll
    for (int r = 0; r < 4; ++r)
      #pragma unroll
      for (int q = 0; q < 4; ++q) {
        gmin[r][q] = fminf(gmin[r][q], __shfl_xor(gmin[r][q], m, 64));
        gmax[r][q] = fmaxf(gmax[r][q], __shfl_xor(gmax[r][q], m, 64));
      }

  if (m16 == 0) {  // lanes 0/16/32/48: quad q-block of 4 consecutive rows per r-tile
    const int rowb = bx * RGR + wave * 64 + quad * 4;
    #pragma unroll
    for (int r = 0; r < 4; ++r)
      #pragma unroll
      for (int q = 0; q < 4; ++q) {
        atomicMax(&umax[rowb + r * 16 + q], ordu(gmax[r][q]));
        atomicMin(&umin[rowb + r * 16 + q], ordu(gmin[r][q]));
      }
  }
}

// ---- kernel 3: per-row decode + loss (32 blocks x 256 threads, 1 row/thread) ----
// Bit-identical to the passing R1 version.
__global__ __launch_bounds__(256) void reduce_k(const unsigned* __restrict__ umax,
                                                const unsigned* __restrict__ umin,
                                                const float* __restrict__ sq,
                                                const int* __restrict__ conf,
                                                unsigned* __restrict__ ctrs,
                                                float* __restrict__ out) {
  __shared__ float red[2][4];
  const int tid = threadIdx.x, bx = blockIdx.x;
  const int wave = tid >> 6, lane = tid & 63;
  const int row = bx * RGR + tid;

  unsigned* g_done = ctrs;
  float*    Ssum   = (float*)(ctrs + 1);
  float*    Csum   = (float*)(ctrs + 2);

  const float hi = deco(umax[row]);
  const float lo = deco(umin[row]);
  float ps = 0.f, pc = 0.f;
  if (conf[row]) {
    const float ap = sqrtf(fmaxf(sq[row] + hi - DEBIAS, 1e-12f));  // hardest positive
    const float an = sqrtf(fmaxf(sq[row] + lo, 1e-12f));           // hardest negative
    ps = fmaxf(ap - an, 0.f);
    pc = 1.f;
  }
  #pragma unroll
  for (int m = 1; m < 64; m <<= 1) {
    ps += __shfl_xor(ps, m, 64);
    pc += __shfl_xor(pc, m, 64);
  }
  if (lane == 0) { red[0][wave] = ps; red[1][wave] = pc; }
  __syncthreads();
  if (tid == 0) {
    atomicAdd(Ssum, red[0][0] + red[0][1] + red[0][2] + red[0][3]);
    atomicAdd(Csum, red[1][0] + red[1][1] + red[1][2] + red[1][3]);
    __threadfence();
    if (atomicAdd(g_done, 1u) == NRG - 1u) {
      const float St = atomicAdd(Ssum, 0.f);
      const float Ct = atomicAdd(Csum, 0.f);
      out[0] = (Ct > 0.f) ? (St / fmaxf(Ct, 1.f)) : 0.f;
    }
  }
}

extern "C" void kernel_launch(void* const* d_in, const int* in_sizes, int n_in,
                              void* d_out, int out_size, void* d_ws, size_t ws_size,
                              hipStream_t stream) {
  const float* x    = (const float*)d_in[0];
  const float* pred = (const float*)d_in[1];
  const int*   tgt  = (const int*)d_in[2];
  float* out = (float*)d_out;

  char* w = (char*)d_ws;
  const size_t arr_bytes = (size_t)NROWS * KB;   // 1.57 MiB each (i8 panel layout)
  char*     xa   = w;
  char*     xbm  = w + arr_bytes;
  float*    sq   = (float*)(w + 2 * arr_bytes);
  int*      conf = (int*)(w + 2 * arr_bytes + (size_t)NROWS * 4);
  unsigned* umax = (unsigned*)(w + 2 * arr_bytes + (size_t)NROWS * 8);
  unsigned* umin = (unsigned*)(w + 2 * arr_bytes + (size_t)NROWS * 12);
  unsigned* ctrs = (unsigned*)(w + 2 * arr_bytes + (size_t)NROWS * 16);

  hipLaunchKernelGGL(prep_k, dim3(NROWS / 4), dim3(256), 0, stream,
                     x, tgt, pred, xa, xbm, sq, conf, umax, umin, ctrs);
  hipLaunchKernelGGL(gram_k, dim3(NRG, NCHUNK), dim3(256), 0, stream,
                     xa, xbm, sq, umax, umin);
  hipLaunchKernelGGL(reduce_k, dim3(NRG), dim3(256), 0, stream,
                     umax, umin, sq, conf, ctrs, out);
}

// Round 6
// 83.097 us; speedup vs baseline: 1.4725x; 1.0367x over previous
//
#include <hip/hip_runtime.h>

#define NROWS 8192
#define DIMX  128              // raw feature dims
#define KB    192              // i8 K: 128 data + 40 one-hot + 3 sqj-encode + 21 pad
#define KSEG  12               // 16B segments per row
#define PTB   24576            // bytes per 128-row panel tile (128*192)
#define NKS   3                // MFMA K-steps of 64
#define NCLS  10
#define GAPV  0.4f
#define DEBIAS 504.03125f      // 2*4*127*127/256 — exact fp32
#define SCL   (-0.0078125f)    // -1/128 — exact fp32
#define RGR   256              // rows per block (4 waves x 64 rows)
#define NRG   (NROWS / RGR)        // 32 rowgroups
#define CHUNK 512              // cols per block
#define NCHUNK (NROWS / CHUNK)     // 16 col-chunks
#define NT    (CHUNK / 16)         // 32 column tiles of 16

typedef __attribute__((ext_vector_type(4))) int i32x4;

__device__ __forceinline__ int q8(float v) {  // round-to-nearest int8 of 16*x
  int q = (int)rintf(16.f * v);
  return q > 127 ? 127 : (q < -127 ? -127 : q);
}

// ---- kernel 1: build i8 PANEL arrays (K=192), sq, confusion, init minmax ----
// panel byte addr = (row>>7)*PTB + kseg*2048 + (row&127)*16 + (byte&15)
// row content: [q8(16x)[0..127] | one-hot dims 128..167 (A:+127/B:-127 on 4
// dims of own class) | dims 168..170: A=(127,127,1), B=-(b1,b2,b3) with
// 127*b1+127*b2+b3 = K_j = rint(128*sq_j) | 0 pad].
// => MFMA acc directly = E = 256*dot - 64516*[same] - K_j; order(E) inverts
//    order(cand = sq_j - 2dot + DEBIAS*[same]) up to K rounding (<=1/256).
__global__ __launch_bounds__(256) void prep_k(const float* __restrict__ x,
                                              const int* __restrict__ tgt,
                                              const float* __restrict__ pred,
                                              char* __restrict__ xa,
                                              char* __restrict__ xbm,
                                              float* __restrict__ sq,
                                              int* __restrict__ conf,
                                              int* __restrict__ emin,
                                              int* __restrict__ emax,
                                              unsigned* __restrict__ ctrs) {
  if (blockIdx.x == 0 && threadIdx.x < 3) ctrs[threadIdx.x] = 0u;
  if (threadIdx.x < 4) {  // init atomic mining slots for this block's 4 rows
    const int r = blockIdx.x * 4 + threadIdx.x;
    emin[r] = 0x7FFFFFFF;          // INT_MAX (mined down; ap/same-class side)
    emax[r] = (int)0x80000000;     // INT_MIN (mined up;  an/diff-class side)
  }

  const int wave = threadIdx.x >> 6;
  const int lane = threadIdx.x & 63;
  const int row  = blockIdx.x * 4 + wave;
  const float2 f2 = ((const float2*)(x + (size_t)row * DIMX))[lane];
  float s = f2.x * f2.x + f2.y * f2.y;
  #pragma unroll
  for (int m = 1; m < 64; m <<= 1) s += __shfl_xor(s, m, 64);

  char* basea = xa  + (size_t)(row >> 7) * PTB + (size_t)(row & 127) * 16;
  char* baseb = xbm + (size_t)(row >> 7) * PTB + (size_t)(row & 127) * 16;
  {  // data elems e=2L,2L+1 -> kseg = L>>3, byte (L&7)*2
    const int q0 = q8(f2.x), q1 = q8(f2.y);
    const unsigned short u = (unsigned short)((q0 & 0xFF) | ((q1 & 0xFF) << 8));
    const size_t off = (size_t)(lane >> 3) * 2048 + (lane & 7) * 2;
    *(unsigned short*)(basea + off) = u;
    *(unsigned short*)(baseb + off) = u;
  }
  const int cls = tgt[row];
  if (lane < 32) {  // aug elems e = 128 + j, j = 2*lane, 2*lane+1
    const int j = 2 * lane;
    unsigned short ua, ub;
    if (lane < 20) {               // class one-hot block (4 dims per class)
      const int c = j >> 2;
      const bool hit = (c == cls);
      ua = hit ? (unsigned short)0x7F7F : 0;  // +127,+127
      ub = hit ? (unsigned short)0x8181 : 0;  // -127,-127
    } else if (lane == 20) {       // j=40,41: K-encode dims, A=(127,127)
      const int K = min((int)rintf(128.f * s), 32385);
      const int t = min(K / 127, 254);
      const int b1 = t < 127 ? t : 127;
      const int b2 = t - b1;
      ua = (unsigned short)0x7F7F;
      ub = (unsigned short)(((-b1) & 0xFF) | (((-b2) & 0xFF) << 8));
    } else if (lane == 21) {       // j=42,43: A=(1,0), B=(-r,0)
      const int K = min((int)rintf(128.f * s), 32385);
      const int t = min(K / 127, 254);
      const int r = min(K - 127 * t, 126);
      ua = (unsigned short)0x0001;
      ub = (unsigned short)((-r) & 0xFF);
    } else { ua = 0; ub = 0; }
    const size_t off = (size_t)(8 + (j >> 4)) * 2048 + (j & 15);
    *(unsigned short*)(basea + off) = ua;
    *(unsigned short*)(baseb + off) = ub;
  }

  if (lane == 0) {
    sq[row] = s;
    const float* pp = pred + (size_t)row * NCLS;
    float v[NCLS];
    #pragma unroll
    for (int c = 0; c < NCLS; ++c) v[c] = pp[c];
    float m1 = v[0]; int i1 = 0;
    #pragma unroll
    for (int c = 1; c < NCLS; ++c)
      if (v[c] > m1) { m1 = v[c]; i1 = c; }
    float m2 = -INFINITY, sum = 0.f;
    #pragma unroll
    for (int c = 0; c < NCLS; ++c) {
      sum += __expf(v[c] - m1);
      if (c != i1) m2 = fmaxf(m2, v[c]);
    }
    const float d01 = (1.f - __expf(m2 - m1)) / sum;
    conf[row] = (d01 <= GAPV) || (i1 != cls);
  }
}

// ---- kernel 2: Gram + INTEGER hard mining — R6 ----
// R4/R5 showed barriers/LDS/occupancy were not the limiter; the per-tile fp32
// epilogue (cvt+fma+min+max = 128 cyc/tile/wave vs 60 cyc MFMA) was. sq_j is
// now folded INTO the MFMA via the K-encode dims, so the epilogue is just
// v_min_i32 + v_max_i32 per cell (64 cyc/tile) and the loop reads nothing but
// B fragments (global/L2-direct, 1-tile register double-buffer, no barriers).
__global__ __launch_bounds__(256)
__attribute__((amdgpu_waves_per_eu(3, 8)))
void gram_k(const char* __restrict__ xa,
            const char* __restrict__ xbm,
            int* __restrict__ emin,
            int* __restrict__ emax) {
  const int tid  = threadIdx.x;
  const int wave = tid >> 6;
  const int lane = tid & 63;
  const int quad = lane >> 4;   // 0..3
  const int m16  = lane & 15;   // 0..15
  const int bx = blockIdx.x, by = blockIdx.y;

  // A fragments: rows bx*256 + wave*64 + rt*16 + m16, kseg = ks*4 + quad
  i32x4 A[4][NKS];
  #pragma unroll
  for (int rt = 0; rt < 4; ++rt) {
    const int rbase = wave * 64 + rt * 16;               // 0..240 within block rows
    const char* pa = xa + (size_t)(bx * 2 + (rbase >> 7)) * PTB
                        + (size_t)((rbase & 127) + m16) * 16;
    #pragma unroll
    for (int ks = 0; ks < NKS; ++ks)
      A[rt][ks] = *(const i32x4*)(pa + (size_t)(ks * 4 + quad) * 2048);
  }
  #pragma unroll
  for (int rt = 0; rt < 4; ++rt)
    #pragma unroll
    for (int ks = 0; ks < NKS; ++ks)
      asm("" : "+v"(A[rt][ks]));   // keep A resident

  int Emin[4][4], Emax[4][4];
  #pragma unroll
  for (int r = 0; r < 4; ++r)
    #pragma unroll
    for (int q = 0; q < 4; ++q) { Emin[r][q] = 0x7FFFFFFF; Emax[r][q] = (int)0x80000000; }

  // per-lane invariant B base; tile u: addr = bl + (u>>3)*PTB + (u&7)*256 + ks*8192
  const char* bl = xbm + (size_t)(by * 4) * PTB + (size_t)m16 * 16 + (size_t)quad * 2048;

  i32x4 Bc[NKS], Bn[NKS];
  #pragma unroll
  for (int ks = 0; ks < NKS; ++ks) Bc[ks] = *(const i32x4*)(bl + ks * 8192);

  for (int s = 0; s < NT / 4; ++s) {        // 8 groups of 4 tiles
    #pragma unroll
    for (int jt = 0; jt < 4; ++jt) {
      const int u  = s * 4 + jt;
      const int un = (u + 1 < NT) ? u + 1 : NT - 1;   // clamp: last prefetch redundant
      const size_t toff = (size_t)(un >> 3) * PTB + (size_t)(un & 7) * 256;
      #pragma unroll
      for (int ks = 0; ks < NKS; ++ks)
        Bn[ks] = *(const i32x4*)(bl + toff + ks * 8192);

      i32x4 acc[4];
      #pragma unroll
      for (int r = 0; r < 4; ++r) acc[r] = (i32x4){0, 0, 0, 0};
      #pragma unroll
      for (int ks = 0; ks < NKS; ++ks)
        #pragma unroll
        for (int r = 0; r < 4; ++r)
          acc[r] = __builtin_amdgcn_mfma_i32_16x16x64_i8(A[r][ks], Bc[ks], acc[r], 0, 0, 0);

      #pragma unroll
      for (int r = 0; r < 4; ++r)
        #pragma unroll
        for (int q = 0; q < 4; ++q) {       // acc = E = 256dot - 64516[same] - K_j
          Emin[r][q] = min(Emin[r][q], acc[r][q]);
          Emax[r][q] = max(Emax[r][q], acc[r][q]);
        }

      #pragma unroll
      for (int ks = 0; ks < NKS; ++ks) Bc[ks] = Bn[ks];   // renamed away by unroll
    }
  }

  // reduce over the 16 cols held across m16 lanes (quad bits preserved)
  #pragma unroll
  for (int m = 1; m <= 8; m <<= 1)
    #pragma unroll
    for (int r = 0; r < 4; ++r)
      #pragma unroll
      for (int q = 0; q < 4; ++q) {
        Emin[r][q] = min(Emin[r][q], __shfl_xor(Emin[r][q], m, 64));
        Emax[r][q] = max(Emax[r][q], __shfl_xor(Emax[r][q], m, 64));
      }

  if (m16 == 0) {  // lanes 0/16/32/48: quad q-block of 4 consecutive rows per r-tile
    const int rowb = bx * RGR + wave * 64 + quad * 4;
    #pragma unroll
    for (int r = 0; r < 4; ++r)
      #pragma unroll
      for (int q = 0; q < 4; ++q) {
        atomicMin(&emin[rowb + r * 16 + q], Emin[r][q]);
        atomicMax(&emax[rowb + r * 16 + q], Emax[r][q]);
      }
  }
}

// ---- kernel 3: per-row decode + loss (32 blocks x 256 threads, 1 row/thread) ----
// cand_max (hardest positive, same-class) = SCL*E_min; cand_min = SCL*E_max.
// SCL*E exact in fp32 (|E| < 2^24, SCL = -2^-7).
__global__ __launch_bounds__(256) void reduce_k(const int* __restrict__ emin,
                                                const int* __restrict__ emax,
                                                const float* __restrict__ sq,
                                                const int* __restrict__ conf,
                                                unsigned* __restrict__ ctrs,
                                                float* __restrict__ out) {
  __shared__ float red[2][4];
  const int tid = threadIdx.x, bx = blockIdx.x;
  const int wave = tid >> 6, lane = tid & 63;
  const int row = bx * RGR + tid;

  unsigned* g_done = ctrs;
  float*    Ssum   = (float*)(ctrs + 1);
  float*    Csum   = (float*)(ctrs + 2);

  const float hi = SCL * (float)emin[row];   // hardest-positive cand (incl +DEBIAS)
  const float lo = SCL * (float)emax[row];   // hardest-negative cand
  float ps = 0.f, pc = 0.f;
  if (conf[row]) {
    const float ap = sqrtf(fmaxf(sq[row] + hi - DEBIAS, 1e-12f));
    const float an = sqrtf(fmaxf(sq[row] + lo, 1e-12f));
    ps = fmaxf(ap - an, 0.f);
    pc = 1.f;
  }
  #pragma unroll
  for (int m = 1; m < 64; m <<= 1) {
    ps += __shfl_xor(ps, m, 64);
    pc += __shfl_xor(pc, m, 64);
  }
  if (lane == 0) { red[0][wave] = ps; red[1][wave] = pc; }
  __syncthreads();
  if (tid == 0) {
    atomicAdd(Ssum, red[0][0] + red[0][1] + red[0][2] + red[0][3]);
    atomicAdd(Csum, red[1][0] + red[1][1] + red[1][2] + red[1][3]);
    __threadfence();
    if (atomicAdd(g_done, 1u) == NRG - 1u) {
      const float St = atomicAdd(Ssum, 0.f);
      const float Ct = atomicAdd(Csum, 0.f);
      out[0] = (Ct > 0.f) ? (St / fmaxf(Ct, 1.f)) : 0.f;
    }
  }
}

extern "C" void kernel_launch(void* const* d_in, const int* in_sizes, int n_in,
                              void* d_out, int out_size, void* d_ws, size_t ws_size,
                              hipStream_t stream) {
  const float* x    = (const float*)d_in[0];
  const float* pred = (const float*)d_in[1];
  const int*   tgt  = (const int*)d_in[2];
  float* out = (float*)d_out;

  char* w = (char*)d_ws;
  const size_t arr_bytes = (size_t)NROWS * KB;   // 1.57 MiB each (i8 panel layout)
  char*  xa   = w;
  char*  xbm  = w + arr_bytes;
  float* sq   = (float*)(w + 2 * arr_bytes);
  int*   conf = (int*)(w + 2 * arr_bytes + (size_t)NROWS * 4);
  int*   emin = (int*)(w + 2 * arr_bytes + (size_t)NROWS * 8);
  int*   emax = (int*)(w + 2 * arr_bytes + (size_t)NROWS * 12);
  unsigned* ctrs = (unsigned*)(w + 2 * arr_bytes + (size_t)NROWS * 16);

  hipLaunchKernelGGL(prep_k, dim3(NROWS / 4), dim3(256), 0, stream,
                     x, tgt, pred, xa, xbm, sq, conf, emin, emax, ctrs);
  hipLaunchKernelGGL(gram_k, dim3(NRG, NCHUNK), dim3(256), 0, stream,
                     xa, xbm, emin, emax);
  hipLaunchKernelGGL(reduce_k, dim3(NRG), dim3(256), 0, stream,
                     emin, emax, sq, conf, ctrs, out);
}